// Round 1
// 447.416 us; speedup vs baseline: 1.1133x; 1.1133x over previous
//
#include <hip/hip_runtime.h>
#include <hip/hip_bf16.h>

static constexpr int N_NODES = 50000;
static constexpr int N_EDGE  = 1000000;
static constexpr int IN_D    = 256;
static constexpr int HID_D   = 128;
static constexpr int OUT_D   = 64;
static constexpr int R_REL   = 2;

typedef __attribute__((ext_vector_type(8))) short short8;   // 8 bf16 = 4 VGPRs
typedef __attribute__((ext_vector_type(4))) float float4v;

static __device__ __forceinline__ unsigned short f2bf(float v) {
    __hip_bfloat16 h = __float2bfloat16(v);
    return *(unsigned short*)&h;
}
static __device__ __forceinline__ float bf2f(unsigned short u) {
    union { unsigned int i; float f; } c; c.i = ((unsigned int)u) << 16; return c.f;
}
// low/high bf16 of a packed u32 -> f32 (1 VALU each: lshl / and)
static __device__ __forceinline__ float bflo(unsigned u) {
    union { unsigned i; float f; } c; c.i = u << 16; return c.f;
}
static __device__ __forceinline__ float bfhi(unsigned u) {
    union { unsigned i; float f; } c; c.i = u & 0xFFFF0000u; return c.f;
}

// ---------------- fp32 -> bf16 bulk convert (4 elems/thread) -------------------
__global__ __launch_bounds__(256) void cvt_bf16_k(
    const float* __restrict__ x, unsigned short* __restrict__ y, long n)
{
    const long i = ((long)blockIdx.x * 256 + threadIdx.x) * 4;
    if (i >= n) return;
    const float4 v = *(const float4*)(x + i);
    ushort4 o;
    o.x = f2bf(v.x); o.y = f2bf(v.y); o.z = f2bf(v.z); o.w = f2bf(v.w);
    *(ushort4*)(y + i) = o;
}

// ---- relation weight prep: W[r][k][o] fp32 -> Wt[n][k] bf16, n = r*Dout+o ----
__global__ __launch_bounds__(256) void wprep_k(
    const float* __restrict__ W, unsigned short* __restrict__ Wt, int K, int Dout)
{
    const int idx = blockIdx.x * 256 + threadIdx.x;
    if (idx >= R_REL * Dout * K) return;
    const int n = idx / K, kk = idx % K;
    const int r = n / Dout, o = n % Dout;
    Wt[(long)n * K + kk] = f2bf(W[((long)r * K + kk) * Dout + o]);
}

// ---- decoder weight split: fp32 -> hi/lo bf16 (same layout) -------------------
__global__ __launch_bounds__(256) void wsplit_k(
    const float* __restrict__ Wsrc, unsigned short* __restrict__ Wh,
    unsigned short* __restrict__ Wl, int n)
{
    const int i = blockIdx.x * 256 + threadIdx.x;
    if (i >= n) return;
    const float v = Wsrc[i];
    const unsigned short hi = f2bf(v);
    Wh[i] = hi;
    Wl[i] = f2bf(v - bf2f(hi));
}

// ---------------- bf16 MFMA GEMM: Cb[M,N] (bf16) = A[M,K] @ Bt[N,K]^T ----------
template<int TM>
__global__ __launch_bounds__(256) void gemm_bf16_k(
    const unsigned short* __restrict__ A, const unsigned short* __restrict__ Bt,
    unsigned short* __restrict__ Cb, int M, int K, int Nn)
{
    constexpr int BM = TM * 32;
    constexpr int LDK = 40;   // 80 B rows: 16B-aligned, 2-way-only bank conflicts
    __shared__ __align__(16) unsigned short As[BM * LDK];
    __shared__ __align__(16) unsigned short Bs[128 * LDK];

    const int tid = threadIdx.x;
    const int wave = tid >> 6, lane = tid & 63;
    const int wm = (wave >> 1) * (TM * 16);
    const int wn = (wave & 1) * 64;
    const int bm = blockIdx.y * BM;
    const int bn = blockIdx.x * 128;
    const int l15 = lane & 15, quad = lane >> 4;

    float4v acc[TM][4];
#pragma unroll
    for (int i = 0; i < TM; ++i)
#pragma unroll
        for (int j = 0; j < 4; ++j) acc[i][j] = (float4v){0.f, 0.f, 0.f, 0.f};

    for (int k0 = 0; k0 < K; k0 += 32) {
        for (int c = tid; c < BM * 4; c += 256) {
            const int r = c >> 2, ch = c & 3;
            const int gr = min(bm + r, M - 1);
            *(uint4*)&As[r * LDK + ch * 8] =
                *(const uint4*)&A[(long)gr * K + k0 + ch * 8];
        }
        for (int c = tid; c < 128 * 4; c += 256) {
            const int r = c >> 2, ch = c & 3;
            *(uint4*)&Bs[r * LDK + ch * 8] =
                *(const uint4*)&Bt[(long)(bn + r) * K + k0 + ch * 8];
        }
        __syncthreads();

        short8 bfrag[4];
#pragma unroll
        for (int nt = 0; nt < 4; ++nt)
            bfrag[nt] = *(const short8*)&Bs[(wn + nt * 16 + l15) * LDK + quad * 8];
#pragma unroll
        for (int mt = 0; mt < TM; ++mt) {
            const short8 afrag = *(const short8*)&As[(wm + mt * 16 + l15) * LDK + quad * 8];
#pragma unroll
            for (int nt = 0; nt < 4; ++nt)
                acc[mt][nt] = __builtin_amdgcn_mfma_f32_16x16x32_bf16(
                    afrag, bfrag[nt], acc[mt][nt], 0, 0, 0);
        }
        __syncthreads();
    }

    // C/D layout: col = lane&15, row = quad*4 + reg (m89-verified)
#pragma unroll
    for (int mt = 0; mt < TM; ++mt)
#pragma unroll
        for (int nt = 0; nt < 4; ++nt) {
            const int n = bn + wn + nt * 16 + l15;
#pragma unroll
            for (int rg = 0; rg < 4; ++rg) {
                const int m = bm + wm + mt * 16 + quad * 4 + rg;
                if (m < M) Cb[(long)m * Nn + n] = f2bf(acc[mt][nt][rg]);
            }
        }
}

// -------- decoder split-bf16 MFMA GEMM: C = (Ah+Al)(Bh+Bl)^T + bias ------------
template<int TM, bool SPLITOUT>
__global__ __launch_bounds__(256) void dec_gemm_k(
    const unsigned short* __restrict__ Ah, const unsigned short* __restrict__ Al,
    const unsigned short* __restrict__ Bh, const unsigned short* __restrict__ Bl,
    const float* __restrict__ bias, float* __restrict__ Cf,
    unsigned short* __restrict__ Ch, unsigned short* __restrict__ Cl,
    int M, int K, int Nn)
{
    constexpr int BM = TM * 32;
    constexpr int LDK = 40;
    __shared__ __align__(16) unsigned short Ash[BM * LDK];
    __shared__ __align__(16) unsigned short Asl[BM * LDK];
    __shared__ __align__(16) unsigned short Bsh[128 * LDK];
    __shared__ __align__(16) unsigned short Bsl[128 * LDK];

    const int tid = threadIdx.x;
    const int wave = tid >> 6, lane = tid & 63;
    const int wm = (wave >> 1) * (TM * 16);
    const int wn = (wave & 1) * 64;
    const int bm = blockIdx.y * BM;
    const int bn = blockIdx.x * 128;
    const int l15 = lane & 15, quad = lane >> 4;

    float4v acc[TM][4];
#pragma unroll
    for (int i = 0; i < TM; ++i)
#pragma unroll
        for (int j = 0; j < 4; ++j) acc[i][j] = (float4v){0.f, 0.f, 0.f, 0.f};

    for (int k0 = 0; k0 < K; k0 += 32) {
        for (int c = tid; c < BM * 4; c += 256) {
            const int r = c >> 2, ch = c & 3;
            const int gr = min(bm + r, M - 1);
            *(uint4*)&Ash[r * LDK + ch * 8] =
                *(const uint4*)&Ah[(long)gr * K + k0 + ch * 8];
            *(uint4*)&Asl[r * LDK + ch * 8] =
                *(const uint4*)&Al[(long)gr * K + k0 + ch * 8];
        }
        for (int c = tid; c < 128 * 4; c += 256) {
            const int r = c >> 2, ch = c & 3;
            *(uint4*)&Bsh[r * LDK + ch * 8] =
                *(const uint4*)&Bh[(long)(bn + r) * K + k0 + ch * 8];
            *(uint4*)&Bsl[r * LDK + ch * 8] =
                *(const uint4*)&Bl[(long)(bn + r) * K + k0 + ch * 8];
        }
        __syncthreads();

        short8 bh[4], bl[4];
#pragma unroll
        for (int nt = 0; nt < 4; ++nt) {
            bh[nt] = *(const short8*)&Bsh[(wn + nt * 16 + l15) * LDK + quad * 8];
            bl[nt] = *(const short8*)&Bsl[(wn + nt * 16 + l15) * LDK + quad * 8];
        }
#pragma unroll
        for (int mt = 0; mt < TM; ++mt) {
            const short8 ah = *(const short8*)&Ash[(wm + mt * 16 + l15) * LDK + quad * 8];
            const short8 al = *(const short8*)&Asl[(wm + mt * 16 + l15) * LDK + quad * 8];
#pragma unroll
            for (int nt = 0; nt < 4; ++nt) {
                acc[mt][nt] = __builtin_amdgcn_mfma_f32_16x16x32_bf16(ah, bh[nt], acc[mt][nt], 0, 0, 0);
                acc[mt][nt] = __builtin_amdgcn_mfma_f32_16x16x32_bf16(al, bh[nt], acc[mt][nt], 0, 0, 0);
                acc[mt][nt] = __builtin_amdgcn_mfma_f32_16x16x32_bf16(ah, bl[nt], acc[mt][nt], 0, 0, 0);
            }
        }
        __syncthreads();
    }

#pragma unroll
    for (int mt = 0; mt < TM; ++mt)
#pragma unroll
        for (int nt = 0; nt < 4; ++nt) {
            const int n = bn + wn + nt * 16 + l15;
            const float bv = bias[n];
#pragma unroll
            for (int rg = 0; rg < 4; ++rg) {
                const int m = bm + wm + mt * 16 + quad * 4 + rg;
                if (m >= M) continue;
                const float v = acc[mt][nt][rg] + bv;
                if (SPLITOUT) {
                    const unsigned short hi = f2bf(v);
                    Ch[(long)m * Nn + n] = hi;
                    Cl[(long)m * Nn + n] = f2bf(v - bf2f(hi));
                } else {
                    Cf[(long)m * Nn + n] = v;
                }
            }
        }
}

// ---------------- q/k dots over bf16 proj [node][R*D] --------------------------
template<int D>
__global__ __launch_bounds__(256) void dotsB_k(
    const unsigned short* __restrict__ projb, const float* __restrict__ q,
    const float* __restrict__ k, float* __restrict__ qd, float* __restrict__ kd,
    int Nn)
{
    const int node = (int)((blockIdx.x * (long)blockDim.x + threadIdx.x) >> 6);
    const int lane = threadIdx.x & 63;
    if (node >= Nn) return;
    const unsigned short* row = projb + (long)node * (2 * D);
    float sq0, sk0, sq1, sk1;
    if (D == 128) {
        const ushort2 a = *(const ushort2*)(row + 2 * lane);
        const ushort2 b = *(const ushort2*)(row + 128 + 2 * lane);
        const float q0 = q[2 * lane], q1 = q[2 * lane + 1];
        const float c0 = k[2 * lane], c1 = k[2 * lane + 1];
        const float a0 = bf2f(a.x), a1 = bf2f(a.y);
        const float b0 = bf2f(b.x), b1 = bf2f(b.y);
        sq0 = fmaf(a0, q0, a1 * q1); sk0 = fmaf(a0, c0, a1 * c1);
        sq1 = fmaf(b0, q0, b1 * q1); sk1 = fmaf(b0, c0, b1 * c1);
    } else {
        const float a0 = bf2f(row[lane]), b0 = bf2f(row[64 + lane]);
        const float q0 = q[lane], c0 = k[lane];
        sq0 = a0 * q0; sk0 = a0 * c0;
        sq1 = b0 * q0; sk1 = b0 * c0;
    }
#pragma unroll
    for (int off = 32; off; off >>= 1) {
        sq0 += __shfl_xor(sq0, off); sk0 += __shfl_xor(sk0, off);
        sq1 += __shfl_xor(sq1, off); sk1 += __shfl_xor(sk1, off);
    }
    if (lane == 0) {
        qd[node] = sq0; qd[Nn + node] = sq1;
        kd[node] = sk0; kd[Nn + node] = sk1;
    }
}

// ---------------- CSR build (rank/scan/place — no atomic->scatter chain) -------
__global__ __launch_bounds__(256) void rank_k(
    const int* __restrict__ dstv, int* __restrict__ cnt,
    int* __restrict__ rank, int E)
{
    const int e = blockIdx.x * blockDim.x + threadIdx.x;
    if (e >= E) return;
    rank[e] = atomicAdd(&cnt[dstv[e]], 1);
}

__global__ __launch_bounds__(256) void scan1_k(
    const int* __restrict__ cnt, int* __restrict__ excl_out,
    int* __restrict__ bsum, int n)
{
    __shared__ int s[256];
    const int t = threadIdx.x;
    const int i = blockIdx.x * 256 + t;
    const int v = (i < n) ? cnt[i] : 0;
    s[t] = v;
    __syncthreads();
    for (int off = 1; off < 256; off <<= 1) {
        const int x = (t >= off) ? s[t - off] : 0;
        __syncthreads();
        s[t] += x;
        __syncthreads();
    }
    if (i < n) excl_out[i] = s[t] - v;
    if (t == 255) bsum[blockIdx.x] = s[255];
}

__global__ __launch_bounds__(256) void scan2_k(
    int* __restrict__ bsum, int* __restrict__ bpre, int nb)
{
    __shared__ int s[256];
    const int t = threadIdx.x;
    const int v = (t < nb) ? bsum[t] : 0;
    s[t] = v;
    __syncthreads();
    for (int off = 1; off < 256; off <<= 1) {
        const int x = (t >= off) ? s[t - off] : 0;
        __syncthreads();
        s[t] += x;
        __syncthreads();
    }
    if (t < nb) bpre[t] = s[t] - v;
}

__global__ __launch_bounds__(256) void scan3_k(
    int* __restrict__ excl, const int* __restrict__ bpre,
    int* __restrict__ offs, int n, int total)
{
    const int i = blockIdx.x * 256 + threadIdx.x;
    if (i >= n) return;
    offs[i] = excl[i] + bpre[i >> 8];
    if (i == 0) offs[n] = total;
}

// place_k: deterministic position, single 8B record write, no atomics.
__global__ __launch_bounds__(256) void place_k(
    const int* __restrict__ srcv, const int* __restrict__ dstv,
    const int* __restrict__ et, const int* __restrict__ rank,
    const int* __restrict__ offs, uint2* __restrict__ recs, int E)
{
    const int e = blockIdx.x * blockDim.x + threadIdx.x;
    if (e >= E) return;
    const int pos = offs[dstv[e]] + rank[e];
    recs[pos] = make_uint2((unsigned)((et[e] << 16) | srcv[e]), (unsigned)e);
}

// -------- layer-1 fused softmax+aggr+ELU, single-pass, LDS-staged --------------
// Per 64-edge chunk: lane-parallel ex/off computed once, staged to LDS as
// (ex, byte_off); gather loop lane-splits the wave in 2 (half-wave per edge,
// uint2 = 8B/lane -> one load covers 2 rows of 256B), unrolled x2 for 2 loads
// in flight. att gets UNNORMALIZED ex; attscale_k applies inv afterwards.
__global__ __launch_bounds__(256) void aggr1_k(
    const int* __restrict__ offs, const uint2* __restrict__ recs,
    const float* __restrict__ qd, const float* __restrict__ kd,
    const unsigned short* __restrict__ projb,
    float* __restrict__ att_ex, float* __restrict__ inv_out,
    unsigned short* __restrict__ h1b, int Nn)
{
    __shared__ uint2 sh[4][64];
    const int wid = threadIdx.x >> 6;
    const int d = blockIdx.x * 4 + wid;
    const int lane = threadIdx.x & 63;
    if (d >= Nn) return;
    const int beg = offs[d], end = offs[d + 1];
    const float qd0 = qd[d], qd1 = qd[Nn + d];
    const char* pb = (const char*)projb;
    const int half = lane >> 5;
    const unsigned lb = (unsigned)((lane & 31) << 3);

    float exsum = 0.f;
    float a0 = 0.f, a1 = 0.f, a2 = 0.f, a3 = 0.f;

    for (int b = beg; b < end; b += 64) {
        const int i = b + lane;
        float ex = 0.f; unsigned off = 0;
        if (i < end) {
            const uint2 r = recs[i];
            const int s = (int)(r.x & 0xFFFFu), t = (int)(r.x >> 16);
            float a = (t ? qd1 : qd0) + kd[t * Nn + s];
            a = a > 0.f ? a : 0.2f * a;
            ex = expf(a);
            att_ex[r.y] = ex;                       // unnormalized; scaled later
            off = ((unsigned)s << 9) | ((unsigned)t << 8);  // s*512 + t*256 bytes
        }
        sh[wid][lane] = make_uint2(__float_as_uint(ex), off);
        float red = ex;
#pragma unroll
        for (int o = 32; o; o >>= 1) red += __shfl_xor(red, o);
        exsum += red;

        const int cnt = min(64, end - b);
        // pad entries (index < 64, >= cnt) hold ex=0/off=0 -> harmless.
        for (int j = 0; j < cnt; j += 4) {
            const uint2 p0 = sh[wid][j + half];
            const uint2 p1 = sh[wid][j + 2 + half];
            const uint2 v0 = *(const uint2*)(pb + (p0.y + lb));
            const uint2 v1 = *(const uint2*)(pb + (p1.y + lb));
            const float w0 = __uint_as_float(p0.x);
            const float w1 = __uint_as_float(p1.x);
            a0 = fmaf(w0, bflo(v0.x), a0);
            a1 = fmaf(w0, bfhi(v0.x), a1);
            a2 = fmaf(w0, bflo(v0.y), a2);
            a3 = fmaf(w0, bfhi(v0.y), a3);
            a0 = fmaf(w1, bflo(v1.x), a0);
            a1 = fmaf(w1, bfhi(v1.x), a1);
            a2 = fmaf(w1, bflo(v1.y), a2);
            a3 = fmaf(w1, bfhi(v1.y), a3);
        }
    }
    const float inv = 1.f / (exsum + 1e-16f);
    if (lane == 0) inv_out[d] = inv;
    a0 += __shfl_xor(a0, 32); a1 += __shfl_xor(a1, 32);
    a2 += __shfl_xor(a2, 32); a3 += __shfl_xor(a3, 32);
    if (half == 0) {
        const float e0 = a0 * inv, e1 = a1 * inv, e2 = a2 * inv, e3 = a3 * inv;
        const float v0 = e0 > 0.f ? e0 : expm1f(e0);
        const float v1 = e1 > 0.f ? e1 : expm1f(e1);
        const float v2 = e2 > 0.f ? e2 : expm1f(e2);
        const float v3 = e3 > 0.f ? e3 : expm1f(e3);
        ushort4 st;
        st.x = f2bf(v0); st.y = f2bf(v1); st.z = f2bf(v2); st.w = f2bf(v3);
        *(ushort4*)&h1b[(long)d * 128 + ((lane & 31) << 2)] = st;
    }
}

// -------- layer-2 fused, single-pass, LDS-staged, 4-way lane split -------------
// Row = 64 bf16 = 128B; quarter-wave (16 lanes x uint2) per edge -> one load
// covers 4 rows; unrolled x2 (8 edges / iter, 2 loads in flight).
__global__ __launch_bounds__(256) void aggr2_k(
    const int* __restrict__ offs, const uint2* __restrict__ recs,
    const float* __restrict__ qd, const float* __restrict__ kd,
    const unsigned short* __restrict__ projb,
    float* __restrict__ att_ex, float* __restrict__ inv_out,
    float* __restrict__ out,
    unsigned short* __restrict__ h2h, unsigned short* __restrict__ h2l, int Nn)
{
    __shared__ uint2 sh[4][64];
    const int wid = threadIdx.x >> 6;
    const int d = blockIdx.x * 4 + wid;
    const int lane = threadIdx.x & 63;
    if (d >= Nn) return;
    const int beg = offs[d], end = offs[d + 1];
    const float qd0 = qd[d], qd1 = qd[Nn + d];
    const char* pb = (const char*)projb;
    const int quarter = lane >> 4;
    const unsigned lb = (unsigned)((lane & 15) << 3);

    float exsum = 0.f;
    float a0 = 0.f, a1 = 0.f, a2 = 0.f, a3 = 0.f;

    for (int b = beg; b < end; b += 64) {
        const int i = b + lane;
        float ex = 0.f; unsigned off = 0;
        if (i < end) {
            const uint2 r = recs[i];
            const int s = (int)(r.x & 0xFFFFu), t = (int)(r.x >> 16);
            float a = (t ? qd1 : qd0) + kd[t * Nn + s];
            a = a > 0.f ? a : 0.2f * a;
            ex = expf(a);
            att_ex[r.y] = ex;
            off = ((unsigned)s << 8) | ((unsigned)t << 7);  // s*256 + t*128 bytes
        }
        sh[wid][lane] = make_uint2(__float_as_uint(ex), off);
        float red = ex;
#pragma unroll
        for (int o = 32; o; o >>= 1) red += __shfl_xor(red, o);
        exsum += red;

        const int cnt = min(64, end - b);
        for (int j = 0; j < cnt; j += 8) {
            const uint2 p0 = sh[wid][j + quarter];
            const uint2 p1 = sh[wid][j + 4 + quarter];
            const uint2 v0 = *(const uint2*)(pb + (p0.y + lb));
            const uint2 v1 = *(const uint2*)(pb + (p1.y + lb));
            const float w0 = __uint_as_float(p0.x);
            const float w1 = __uint_as_float(p1.x);
            a0 = fmaf(w0, bflo(v0.x), a0);
            a1 = fmaf(w0, bfhi(v0.x), a1);
            a2 = fmaf(w0, bflo(v0.y), a2);
            a3 = fmaf(w0, bfhi(v0.y), a3);
            a0 = fmaf(w1, bflo(v1.x), a0);
            a1 = fmaf(w1, bfhi(v1.x), a1);
            a2 = fmaf(w1, bflo(v1.y), a2);
            a3 = fmaf(w1, bfhi(v1.y), a3);
        }
    }
    const float inv = 1.f / (exsum + 1e-16f);
    if (lane == 0) inv_out[d] = inv;
    a0 += __shfl_xor(a0, 32); a1 += __shfl_xor(a1, 32);
    a2 += __shfl_xor(a2, 32); a3 += __shfl_xor(a3, 32);
    a0 += __shfl_xor(a0, 16); a1 += __shfl_xor(a1, 16);
    a2 += __shfl_xor(a2, 16); a3 += __shfl_xor(a3, 16);
    if (quarter == 0) {
        const float e0 = a0 * inv, e1 = a1 * inv, e2 = a2 * inv, e3 = a3 * inv;
        const float v0 = e0 > 0.f ? e0 : expm1f(e0);
        const float v1 = e1 > 0.f ? e1 : expm1f(e1);
        const float v2 = e2 > 0.f ? e2 : expm1f(e2);
        const float v3 = e3 > 0.f ? e3 : expm1f(e3);
        const int l16 = lane & 15;
        float4 fo; fo.x = v0; fo.y = v1; fo.z = v2; fo.w = v3;
        *(float4*)&out[(long)d * 64 + (l16 << 2)] = fo;
        ushort4 sh4, sl4;
        const unsigned short h0 = f2bf(v0), h1 = f2bf(v1);
        const unsigned short h2 = f2bf(v2), h3 = f2bf(v3);
        sh4.x = h0; sh4.y = h1; sh4.z = h2; sh4.w = h3;
        sl4.x = f2bf(v0 - bf2f(h0)); sl4.y = f2bf(v1 - bf2f(h1));
        sl4.z = f2bf(v2 - bf2f(h2)); sl4.w = f2bf(v3 - bf2f(h3));
        *(ushort4*)&h2h[(long)d * 64 + (l16 << 2)] = sh4;
        *(ushort4*)&h2l[(long)d * 64 + (l16 << 2)] = sl4;
    }
}

// -------- normalize attention for both layers in one edge-parallel pass --------
__global__ __launch_bounds__(256) void attscale_k(
    const int* __restrict__ dstv, const float* __restrict__ inv1,
    const float* __restrict__ inv2, float* __restrict__ att1,
    float* __restrict__ att2, int E)
{
    const int e = blockIdx.x * 256 + threadIdx.x;
    if (e >= E) return;
    const int dd = dstv[e];
    att1[e] *= inv1[dd];
    att2[e] *= inv2[dd];
}

extern "C" void kernel_launch(void* const* d_in, const int* in_sizes, int n_in,
                              void* d_out, int out_size, void* d_ws, size_t ws_size,
                              hipStream_t stream)
{
    const float* features = (const float*)d_in[0];
    const int*   eidx     = (const int*)d_in[1];
    const int*   etype    = (const int*)d_in[2];
    const float* W1       = (const float*)d_in[3];
    const float* q1       = (const float*)d_in[4];
    const float* k1       = (const float*)d_in[5];
    const float* W2       = (const float*)d_in[6];
    const float* q2       = (const float*)d_in[7];
    const float* k2       = (const float*)d_in[8];
    const float* dw1      = (const float*)d_in[9];
    const float* db1      = (const float*)d_in[10];
    const float* dw2      = (const float*)d_in[11];
    const float* db2      = (const float*)d_in[12];

    const int* srcv = eidx;
    const int* dstv = eidx + N_EDGE;

    float* out_h2 = (float*)d_out;                  // N x 64
    float* out_h3 = out_h2 + (long)N_NODES * OUT_D; // N x 256
    float* att1   = out_h3 + (long)N_NODES * IN_D;  // E
    float* att2   = att1 + N_EDGE;                  // E

    // ---- workspace carve-up ----
    // Liveness: rank aliases projb1's first 4 MB — rank dies at place_k, and
    // projb1 is first written by gemm_bf16_k which launches AFTER place_k.
    // inv1/inv2 live from aggr1/aggr2 until attscale_k (last kernel); they sit
    // in the dead scan-scratch gap [53.5M, 57.3M) which nothing else touches
    // after scan3.
    char* W = (char*)d_ws;
    int* rank = (int*)W;                                       // [0, 4M)  (aliases projb1)
    unsigned short* projb1 = (unsigned short*)(W);             // [0, 25.6M)
    unsigned short* projb2 = (unsigned short*)(W);             // alias
    unsigned short* hidh   = (unsigned short*)(W);             // [0, 12.8M) after aggr2
    unsigned short* hidl   = (unsigned short*)(W + 12800000);
    unsigned short* featb  = (unsigned short*)(W + 25600000);  // [25.6M, 51.2M)
    unsigned short* h1b    = featb;                            // alias after gemm1
    unsigned short* h2h    = (unsigned short*)(W + 25600000 + 12800000);
    unsigned short* h2l    = (unsigned short*)(W + 25600000 + 19200000);
    float* qd1 = (float*)(W + 51200000);
    float* kd1 = qd1 + 2 * N_NODES;
    float* qd2 = kd1 + 2 * N_NODES;
    float* kd2 = qd2 + 2 * N_NODES;
    int* cnt    = (int*)(kd2 + 2 * N_NODES);        // ends 53.0M
    int* offs   = cnt + N_NODES;                    // ends 53.200M
    int* bsum   = offs + N_NODES + 1;
    int* bpre   = bsum + 256;
    int* excl   = bpre + 256;                       // ends 53.402M
    float* inv1 = (float*)(W + 53500000);           // [53.5M, 53.7M)
    float* inv2 = inv1 + N_NODES;                   // [53.7M, 53.9M)
    uint2* recs = (uint2*)(W + 57300000);           // [57.3M, 65.3M), 8-aligned
    unsigned short* Wc1t = (unsigned short*)(W + 65300000);    // 65536 us
    unsigned short* Wc2t = Wc1t + 65536;                       // 16384 us
    unsigned short* dw1h = Wc2t + 16384;                       // 8192
    unsigned short* dw1l = dw1h + 8192;
    unsigned short* dw2h = dw1l + 8192;                        // 32768
    unsigned short* dw2l = dw2h + 32768;

    const int NB = (N_NODES + 255) / 256;

    // ---- prep: conversions + CSR build ----
    cvt_bf16_k<<<(int)(((long)N_NODES * IN_D / 4 + 255) / 256), 256, 0, stream>>>(
        features, featb, (long)N_NODES * IN_D);
    wprep_k<<<(R_REL * HID_D * IN_D + 255) / 256, 256, 0, stream>>>(W1, Wc1t, IN_D, HID_D);
    wprep_k<<<(R_REL * OUT_D * HID_D + 255) / 256, 256, 0, stream>>>(W2, Wc2t, HID_D, OUT_D);
    wsplit_k<<<(HID_D * OUT_D + 255) / 256, 256, 0, stream>>>(dw1, dw1h, dw1l, HID_D * OUT_D);
    wsplit_k<<<(IN_D * HID_D + 255) / 256, 256, 0, stream>>>(dw2, dw2h, dw2l, IN_D * HID_D);

    hipMemsetAsync(cnt, 0, sizeof(int) * N_NODES, stream);
    rank_k<<<(N_EDGE + 255) / 256, 256, 0, stream>>>(dstv, cnt, rank, N_EDGE);
    scan1_k<<<NB, 256, 0, stream>>>(cnt, excl, bsum, N_NODES);
    scan2_k<<<1, 256, 0, stream>>>(bsum, bpre, NB);
    scan3_k<<<NB, 256, 0, stream>>>(excl, bpre, offs, N_NODES, N_EDGE);
    place_k<<<(N_EDGE + 255) / 256, 256, 0, stream>>>(
        srcv, dstv, etype, rank, offs, recs, N_EDGE);

    // ---- layer 1 ----
    gemm_bf16_k<4><<<dim3(2, (N_NODES + 127) / 128), 256, 0, stream>>>(
        featb, Wc1t, projb1, N_NODES, IN_D, 2 * HID_D);
    dotsB_k<128><<<(int)(((long)N_NODES * 64 + 255) / 256), 256, 0, stream>>>(
        projb1, q1, k1, qd1, kd1, N_NODES);
    aggr1_k<<<(N_NODES + 3) / 4, 256, 0, stream>>>(
        offs, recs, qd1, kd1, projb1, att1, inv1, h1b, N_NODES);

    // ---- layer 2 ----
    gemm_bf16_k<4><<<dim3(1, (N_NODES + 127) / 128), 256, 0, stream>>>(
        h1b, Wc2t, projb2, N_NODES, HID_D, 2 * OUT_D);
    dotsB_k<64><<<(int)(((long)N_NODES * 64 + 255) / 256), 256, 0, stream>>>(
        projb2, q2, k2, qd2, kd2, N_NODES);
    aggr2_k<<<(N_NODES + 3) / 4, 256, 0, stream>>>(
        offs, recs, qd2, kd2, projb2, att2, inv2, out_h2, h2h, h2l, N_NODES);

    // ---- attention normalization (both layers, one pass over E) ----
    attscale_k<<<(N_EDGE + 255) / 256, 256, 0, stream>>>(
        dstv, inv1, inv2, att1, att2, N_EDGE);

    // ---- decoder (split-bf16 MFMA, fp32-accurate) ----
    dec_gemm_k<4, true><<<dim3(1, (N_NODES + 127) / 128), 256, 0, stream>>>(
        h2h, h2l, dw1h, dw1l, db1, nullptr, hidh, hidl, N_NODES, OUT_D, HID_D);
    dec_gemm_k<4, false><<<dim3(2, (N_NODES + 127) / 128), 256, 0, stream>>>(
        hidh, hidl, dw2h, dw2l, db2, out_h3, nullptr, nullptr, N_NODES, HID_D, IN_D);
}

// Round 3
// 420.780 us; speedup vs baseline: 1.1838x; 1.0633x over previous
//
#include <hip/hip_runtime.h>
#include <hip/hip_bf16.h>

static constexpr int N_NODES = 50000;
static constexpr int N_EDGE  = 1000000;
static constexpr int IN_D    = 256;
static constexpr int HID_D   = 128;
static constexpr int OUT_D   = 64;
static constexpr int R_REL   = 2;

typedef __attribute__((ext_vector_type(8))) short short8;            // 8 bf16 = 4 VGPRs
typedef __attribute__((ext_vector_type(8))) unsigned short ushort8;  // store type
typedef __attribute__((ext_vector_type(4))) float float4v;

static __device__ __forceinline__ unsigned short f2bf(float v) {
    __hip_bfloat16 h = __float2bfloat16(v);
    return *(unsigned short*)&h;
}
static __device__ __forceinline__ float bf2f(unsigned short u) {
    union { unsigned int i; float f; } c; c.i = ((unsigned int)u) << 16; return c.f;
}
// low/high bf16 of a packed u32 -> f32 (1 VALU each: lshl / and)
static __device__ __forceinline__ float bflo(unsigned u) {
    union { unsigned i; float f; } c; c.i = u << 16; return c.f;
}
static __device__ __forceinline__ float bfhi(unsigned u) {
    union { unsigned i; float f; } c; c.i = u & 0xFFFF0000u; return c.f;
}
static __device__ __forceinline__ float u2f(unsigned u) {
    union { unsigned i; float f; } c; c.i = u; return c.f;
}
static __device__ __forceinline__ unsigned f2u(float f) {
    union { unsigned i; float f; } c; c.f = f; return c.i;
}
// accumulate 8 bf16 (one uint4) scaled by w into a[0..7]
static __device__ __forceinline__ void acc8(float w, uint4 v, float (&a)[8]) {
    a[0] = fmaf(w, bflo(v.x), a[0]); a[1] = fmaf(w, bfhi(v.x), a[1]);
    a[2] = fmaf(w, bflo(v.y), a[2]); a[3] = fmaf(w, bfhi(v.y), a[3]);
    a[4] = fmaf(w, bflo(v.z), a[4]); a[5] = fmaf(w, bfhi(v.z), a[5]);
    a[6] = fmaf(w, bflo(v.w), a[6]); a[7] = fmaf(w, bfhi(v.w), a[7]);
}

// ---- merged weight prep: W1/W2 transpose-convert + dec weight hi/lo split ----
__global__ __launch_bounds__(256) void prep_k(
    const float* __restrict__ W1, const float* __restrict__ W2,
    const float* __restrict__ dw1, const float* __restrict__ dw2,
    unsigned short* __restrict__ Wc1t, unsigned short* __restrict__ Wc2t,
    unsigned short* __restrict__ dw1h, unsigned short* __restrict__ dw1l,
    unsigned short* __restrict__ dw2h, unsigned short* __restrict__ dw2l)
{
    int idx = blockIdx.x * 256 + threadIdx.x;
    if (idx < R_REL * HID_D * IN_D) {                       // 65536
        const int n = idx / IN_D, kk = idx % IN_D;
        const int r = n / HID_D, o = n % HID_D;
        Wc1t[(long)n * IN_D + kk] = f2bf(W1[((long)r * IN_D + kk) * HID_D + o]);
        return;
    }
    idx -= R_REL * HID_D * IN_D;
    if (idx < R_REL * OUT_D * HID_D) {                      // 16384
        const int n = idx / HID_D, kk = idx % HID_D;
        const int r = n / OUT_D, o = n % OUT_D;
        Wc2t[(long)n * HID_D + kk] = f2bf(W2[((long)r * HID_D + kk) * OUT_D + o]);
        return;
    }
    idx -= R_REL * OUT_D * HID_D;
    if (idx < HID_D * OUT_D) {                              // 8192
        const float v = dw1[idx];
        const unsigned short hi = f2bf(v);
        dw1h[idx] = hi; dw1l[idx] = f2bf(v - bf2f(hi));
        return;
    }
    idx -= HID_D * OUT_D;
    if (idx < IN_D * HID_D) {                               // 32768
        const float v = dw2[idx];
        const unsigned short hi = f2bf(v);
        dw2h[idx] = hi; dw2l[idx] = f2bf(v - bf2f(hi));
    }
}

// ---------------- bf16 MFMA GEMM: Cb[M,N] (bf16) = A[M,K] @ Bt[N,K]^T ----------
// CVT=true: A is fp32 (Af), converted to bf16 during LDS staging (folds the old
// cvt_bf16_k kernel into gemm1's staging loads).
template<int TM, bool CVT>
__global__ __launch_bounds__(256) void gemm_bf16_k(
    const unsigned short* __restrict__ A, const float* __restrict__ Af,
    const unsigned short* __restrict__ Bt,
    unsigned short* __restrict__ Cb, int M, int K, int Nn)
{
    constexpr int BM = TM * 32;
    constexpr int LDK = 40;   // 80 B rows: 16B-aligned, 2-way-only bank conflicts
    __shared__ __align__(16) unsigned short As[BM * LDK];
    __shared__ __align__(16) unsigned short Bs[128 * LDK];

    const int tid = threadIdx.x;
    const int wave = tid >> 6, lane = tid & 63;
    const int wm = (wave >> 1) * (TM * 16);
    const int wn = (wave & 1) * 64;
    const int bm = blockIdx.y * BM;
    const int bn = blockIdx.x * 128;
    const int l15 = lane & 15, quad = lane >> 4;

    float4v acc[TM][4];
#pragma unroll
    for (int i = 0; i < TM; ++i)
#pragma unroll
        for (int j = 0; j < 4; ++j) acc[i][j] = (float4v){0.f, 0.f, 0.f, 0.f};

    for (int k0 = 0; k0 < K; k0 += 32) {
        for (int c = tid; c < BM * 4; c += 256) {
            const int r = c >> 2, ch = c & 3;
            const int gr = min(bm + r, M - 1);
            if constexpr (CVT) {
                const float4 f0 = *(const float4*)&Af[(long)gr * K + k0 + ch * 8];
                const float4 f1 = *(const float4*)&Af[(long)gr * K + k0 + ch * 8 + 4];
                uint4 o;
                o.x = (unsigned)f2bf(f0.x) | ((unsigned)f2bf(f0.y) << 16);
                o.y = (unsigned)f2bf(f0.z) | ((unsigned)f2bf(f0.w) << 16);
                o.z = (unsigned)f2bf(f1.x) | ((unsigned)f2bf(f1.y) << 16);
                o.w = (unsigned)f2bf(f1.z) | ((unsigned)f2bf(f1.w) << 16);
                *(uint4*)&As[r * LDK + ch * 8] = o;
            } else {
                *(uint4*)&As[r * LDK + ch * 8] =
                    *(const uint4*)&A[(long)gr * K + k0 + ch * 8];
            }
        }
        for (int c = tid; c < 128 * 4; c += 256) {
            const int r = c >> 2, ch = c & 3;
            *(uint4*)&Bs[r * LDK + ch * 8] =
                *(const uint4*)&Bt[(long)(bn + r) * K + k0 + ch * 8];
        }
        __syncthreads();

        short8 bfrag[4];
#pragma unroll
        for (int nt = 0; nt < 4; ++nt)
            bfrag[nt] = *(const short8*)&Bs[(wn + nt * 16 + l15) * LDK + quad * 8];
#pragma unroll
        for (int mt = 0; mt < TM; ++mt) {
            const short8 afrag = *(const short8*)&As[(wm + mt * 16 + l15) * LDK + quad * 8];
#pragma unroll
            for (int nt = 0; nt < 4; ++nt)
                acc[mt][nt] = __builtin_amdgcn_mfma_f32_16x16x32_bf16(
                    afrag, bfrag[nt], acc[mt][nt], 0, 0, 0);
        }
        __syncthreads();
    }

    // C/D layout: col = lane&15, row = quad*4 + reg (m89-verified)
#pragma unroll
    for (int mt = 0; mt < TM; ++mt)
#pragma unroll
        for (int nt = 0; nt < 4; ++nt) {
            const int n = bn + wn + nt * 16 + l15;
#pragma unroll
            for (int rg = 0; rg < 4; ++rg) {
                const int m = bm + wm + mt * 16 + quad * 4 + rg;
                if (m < M) Cb[(long)m * Nn + n] = f2bf(acc[mt][nt][rg]);
            }
        }
}

// -------- decoder split-bf16 MFMA GEMM: C = (Ah+Al)(Bh+Bl)^T + bias ------------
template<int TM, bool SPLITOUT>
__global__ __launch_bounds__(256) void dec_gemm_k(
    const unsigned short* __restrict__ Ah, const unsigned short* __restrict__ Al,
    const unsigned short* __restrict__ Bh, const unsigned short* __restrict__ Bl,
    const float* __restrict__ bias, float* __restrict__ Cf,
    unsigned short* __restrict__ Ch, unsigned short* __restrict__ Cl,
    int M, int K, int Nn)
{
    constexpr int BM = TM * 32;
    constexpr int LDK = 40;
    __shared__ __align__(16) unsigned short Ash[BM * LDK];
    __shared__ __align__(16) unsigned short Asl[BM * LDK];
    __shared__ __align__(16) unsigned short Bsh[128 * LDK];
    __shared__ __align__(16) unsigned short Bsl[128 * LDK];

    const int tid = threadIdx.x;
    const int wave = tid >> 6, lane = tid & 63;
    const int wm = (wave >> 1) * (TM * 16);
    const int wn = (wave & 1) * 64;
    const int bm = blockIdx.y * BM;
    const int bn = blockIdx.x * 128;
    const int l15 = lane & 15, quad = lane >> 4;

    float4v acc[TM][4];
#pragma unroll
    for (int i = 0; i < TM; ++i)
#pragma unroll
        for (int j = 0; j < 4; ++j) acc[i][j] = (float4v){0.f, 0.f, 0.f, 0.f};

    for (int k0 = 0; k0 < K; k0 += 32) {
        for (int c = tid; c < BM * 4; c += 256) {
            const int r = c >> 2, ch = c & 3;
            const int gr = min(bm + r, M - 1);
            *(uint4*)&Ash[r * LDK + ch * 8] =
                *(const uint4*)&Ah[(long)gr * K + k0 + ch * 8];
            *(uint4*)&Asl[r * LDK + ch * 8] =
                *(const uint4*)&Al[(long)gr * K + k0 + ch * 8];
        }
        for (int c = tid; c < 128 * 4; c += 256) {
            const int r = c >> 2, ch = c & 3;
            *(uint4*)&Bsh[r * LDK + ch * 8] =
                *(const uint4*)&Bh[(long)(bn + r) * K + k0 + ch * 8];
            *(uint4*)&Bsl[r * LDK + ch * 8] =
                *(const uint4*)&Bl[(long)(bn + r) * K + k0 + ch * 8];
        }
        __syncthreads();

        short8 bh[4], bl[4];
#pragma unroll
        for (int nt = 0; nt < 4; ++nt) {
            bh[nt] = *(const short8*)&Bsh[(wn + nt * 16 + l15) * LDK + quad * 8];
            bl[nt] = *(const short8*)&Bsl[(wn + nt * 16 + l15) * LDK + quad * 8];
        }
#pragma unroll
        for (int mt = 0; mt < TM; ++mt) {
            const short8 ah = *(const short8*)&Ash[(wm + mt * 16 + l15) * LDK + quad * 8];
            const short8 al = *(const short8*)&Asl[(wm + mt * 16 + l15) * LDK + quad * 8];
#pragma unroll
            for (int nt = 0; nt < 4; ++nt) {
                acc[mt][nt] = __builtin_amdgcn_mfma_f32_16x16x32_bf16(ah, bh[nt], acc[mt][nt], 0, 0, 0);
                acc[mt][nt] = __builtin_amdgcn_mfma_f32_16x16x32_bf16(al, bh[nt], acc[mt][nt], 0, 0, 0);
                acc[mt][nt] = __builtin_amdgcn_mfma_f32_16x16x32_bf16(ah, bl[nt], acc[mt][nt], 0, 0, 0);
            }
        }
        __syncthreads();
    }

#pragma unroll
    for (int mt = 0; mt < TM; ++mt)
#pragma unroll
        for (int nt = 0; nt < 4; ++nt) {
            const int n = bn + wn + nt * 16 + l15;
            const float bv = bias[n];
#pragma unroll
            for (int rg = 0; rg < 4; ++rg) {
                const int m = bm + wm + mt * 16 + quad * 4 + rg;
                if (m >= M) continue;
                const float v = acc[mt][nt][rg] + bv;
                if (SPLITOUT) {
                    const unsigned short hi = f2bf(v);
                    Ch[(long)m * Nn + n] = hi;
                    Cl[(long)m * Nn + n] = f2bf(v - bf2f(hi));
                } else {
                    Cf[(long)m * Nn + n] = v;
                }
            }
        }
}

// ---------------- q/k dots over bf16 proj [node][R*D] --------------------------
// qd layout: interleaved [node][2] so consumers read one float2.
template<int D>
__global__ __launch_bounds__(256) void dotsB_k(
    const unsigned short* __restrict__ projb, const float* __restrict__ q,
    const float* __restrict__ k, float* __restrict__ qd, float* __restrict__ kd,
    int Nn)
{
    const int node = (int)((blockIdx.x * (long)blockDim.x + threadIdx.x) >> 6);
    const int lane = threadIdx.x & 63;
    if (node >= Nn) return;
    const unsigned short* row = projb + (long)node * (2 * D);
    float sq0, sk0, sq1, sk1;
    if (D == 128) {
        const ushort2 a = *(const ushort2*)(row + 2 * lane);
        const ushort2 b = *(const ushort2*)(row + 128 + 2 * lane);
        const float q0 = q[2 * lane], q1 = q[2 * lane + 1];
        const float c0 = k[2 * lane], c1 = k[2 * lane + 1];
        const float a0 = bf2f(a.x), a1 = bf2f(a.y);
        const float b0 = bf2f(b.x), b1 = bf2f(b.y);
        sq0 = fmaf(a0, q0, a1 * q1); sk0 = fmaf(a0, c0, a1 * c1);
        sq1 = fmaf(b0, q0, b1 * q1); sk1 = fmaf(b0, c0, b1 * c1);
    } else {
        const float a0 = bf2f(row[lane]), b0 = bf2f(row[64 + lane]);
        const float q0 = q[lane], c0 = k[lane];
        sq0 = a0 * q0; sk0 = a0 * c0;
        sq1 = b0 * q0; sk1 = b0 * c0;
    }
#pragma unroll
    for (int off = 32; off; off >>= 1) {
        sq0 += __shfl_xor(sq0, off); sk0 += __shfl_xor(sk0, off);
        sq1 += __shfl_xor(sq1, off); sk1 += __shfl_xor(sk1, off);
    }
    if (lane == 0) {
        *(float2*)&qd[2 * node] = make_float2(sq0, sq1);
        kd[node] = sk0; kd[Nn + node] = sk1;
    }
}

// ---------------- CSR build (rank/scan/place — no atomic->scatter chain) -------
__global__ __launch_bounds__(256) void rank_k(
    const int* __restrict__ dstv, int* __restrict__ cnt,
    int* __restrict__ rank, int E)
{
    const int e = blockIdx.x * blockDim.x + threadIdx.x;
    if (e >= E) return;
    rank[e] = atomicAdd(&cnt[dstv[e]], 1);
}

__global__ __launch_bounds__(256) void scan1_k(
    const int* __restrict__ cnt, int* __restrict__ excl_out,
    int* __restrict__ bsum, int n)
{
    __shared__ int s[256];
    const int t = threadIdx.x;
    const int i = blockIdx.x * 256 + t;
    const int v = (i < n) ? cnt[i] : 0;
    s[t] = v;
    __syncthreads();
    for (int off = 1; off < 256; off <<= 1) {
        const int x = (t >= off) ? s[t - off] : 0;
        __syncthreads();
        s[t] += x;
        __syncthreads();
    }
    if (i < n) excl_out[i] = s[t] - v;
    if (t == 255) bsum[blockIdx.x] = s[255];
}

__global__ __launch_bounds__(256) void scan2_k(
    int* __restrict__ bsum, int* __restrict__ bpre, int nb)
{
    __shared__ int s[256];
    const int t = threadIdx.x;
    const int v = (t < nb) ? bsum[t] : 0;
    s[t] = v;
    __syncthreads();
    for (int off = 1; off < 256; off <<= 1) {
        const int x = (t >= off) ? s[t - off] : 0;
        __syncthreads();
        s[t] += x;
        __syncthreads();
    }
    if (t < nb) bpre[t] = s[t] - v;
}

__global__ __launch_bounds__(256) void scan3_k(
    int* __restrict__ excl, const int* __restrict__ bpre,
    int* __restrict__ offs, int n, int total)
{
    const int i = blockIdx.x * 256 + threadIdx.x;
    if (i >= n) return;
    offs[i] = excl[i] + bpre[i >> 8];
    if (i == 0) offs[n] = total;
}

// place_k: deterministic position, single 4B record write, no atomics.
// record = (etype << 16) | src   (src < 65536 since N_NODES = 50000)
__global__ __launch_bounds__(256) void place_k(
    const int* __restrict__ srcv, const int* __restrict__ dstv,
    const int* __restrict__ et, const int* __restrict__ rank,
    const int* __restrict__ offs, unsigned* __restrict__ recs, int E)
{
    const int e = blockIdx.x * blockDim.x + threadIdx.x;
    if (e >= E) return;
    const int pos = offs[dstv[e]] + rank[e];
    recs[pos] = (unsigned)((et[e] << 16) | srcv[e]);
}

// -------- layer-1 fused softmax+aggr+ELU, quarter-wave uint4 gather ------------
// Row = 128 bf16 = 256B = 16 lanes x uint4; 4 edges per load, 4 loads in flight
// covering 16 edges per burst. No attention writes here (att_k recomputes).
__global__ __launch_bounds__(256) void aggr1_k(
    const int* __restrict__ offs, const unsigned* __restrict__ recs,
    const float* __restrict__ qd, const float* __restrict__ kd,
    const unsigned short* __restrict__ projb,
    float* __restrict__ inv_out, unsigned short* __restrict__ h1b, int Nn)
{
    __shared__ uint2 sh[4][64];
    const int wid = threadIdx.x >> 6;
    const int d = blockIdx.x * 4 + wid;
    const int lane = threadIdx.x & 63;
    if (d >= Nn) return;
    const int beg = offs[d], end = offs[d + 1];
    const float2 qv = *(const float2*)&qd[2 * d];
    const char* pb = (const char*)projb;
    const int quarter = lane >> 4, l15 = lane & 15;
    const unsigned lb = (unsigned)(l15 << 4);            // 16B per lane
    uint2* shl = sh[wid];

    float exsum = 0.f;
    float a[8] = {0.f, 0.f, 0.f, 0.f, 0.f, 0.f, 0.f, 0.f};

    for (int b = beg; b < end; b += 64) {
        const int i = b + lane;
        float ex = 0.f; unsigned off = 0;
        if (i < end) {
            const unsigned rx = recs[i];
            const int s = (int)(rx & 0xFFFFu), t = (int)(rx >> 16);
            float av = (t ? qv.y : qv.x) + kd[t * Nn + s];
            av = av > 0.f ? av : 0.2f * av;
            ex = __expf(av);
            off = ((unsigned)s << 9) | ((unsigned)t << 8);  // s*512 + t*256 bytes
        }
        shl[lane] = make_uint2(f2u(ex), off);
        exsum += ex;                                     // reduced once at end

        const int cnt = min(64, end - b);
        for (int j = 0; j < cnt; j += 16) {
            const uint2 p0 = shl[j + quarter];
            const uint2 p1 = shl[j + 4 + quarter];
            const uint2 p2 = shl[j + 8 + quarter];
            const uint2 p3 = shl[j + 12 + quarter];
            const uint4 v0 = *(const uint4*)(pb + (p0.y + lb));
            const uint4 v1 = *(const uint4*)(pb + (p1.y + lb));
            const uint4 v2 = *(const uint4*)(pb + (p2.y + lb));
            const uint4 v3 = *(const uint4*)(pb + (p3.y + lb));
            acc8(u2f(p0.x), v0, a);
            acc8(u2f(p1.x), v1, a);
            acc8(u2f(p2.x), v2, a);
            acc8(u2f(p3.x), v3, a);
        }
    }
#pragma unroll
    for (int o = 32; o; o >>= 1) exsum += __shfl_xor(exsum, o);
    const float inv = 1.f / (exsum + 1e-16f);
    if (lane == 0) inv_out[d] = inv;
#pragma unroll
    for (int q = 0; q < 8; ++q) {
        a[q] += __shfl_xor(a[q], 32);
        a[q] += __shfl_xor(a[q], 16);
    }
    if (quarter == 0) {
        ushort8 st;
#pragma unroll
        for (int q = 0; q < 8; ++q) {
            const float e = a[q] * inv;
            st[q] = f2bf(e > 0.f ? e : expm1f(e));
        }
        *(ushort8*)&h1b[(long)d * 128 + (l15 << 3)] = st;   // dims l15*8..+7
    }
}

// -------- layer-2 fused, eighth-wave uint4 gather ------------------------------
// Row = 64 bf16 = 128B = 8 lanes x uint4; 8 edges per load, 4 loads in flight
// covering 32 edges per burst (avg degree 20 -> usually one burst per node).
__global__ __launch_bounds__(256) void aggr2_k(
    const int* __restrict__ offs, const unsigned* __restrict__ recs,
    const float* __restrict__ qd, const float* __restrict__ kd,
    const unsigned short* __restrict__ projb,
    float* __restrict__ inv_out, float* __restrict__ out,
    unsigned short* __restrict__ h2h, unsigned short* __restrict__ h2l, int Nn)
{
    __shared__ uint2 sh[4][64];
    const int wid = threadIdx.x >> 6;
    const int d = blockIdx.x * 4 + wid;
    const int lane = threadIdx.x & 63;
    if (d >= Nn) return;
    const int beg = offs[d], end = offs[d + 1];
    const float2 qv = *(const float2*)&qd[2 * d];
    const char* pb = (const char*)projb;
    const int eighth = lane >> 3, l7 = lane & 7;
    const unsigned lb = (unsigned)(l7 << 4);             // 16B per lane
    uint2* shl = sh[wid];

    float exsum = 0.f;
    float a[8] = {0.f, 0.f, 0.f, 0.f, 0.f, 0.f, 0.f, 0.f};

    for (int b = beg; b < end; b += 64) {
        const int i = b + lane;
        float ex = 0.f; unsigned off = 0;
        if (i < end) {
            const unsigned rx = recs[i];
            const int s = (int)(rx & 0xFFFFu), t = (int)(rx >> 16);
            float av = (t ? qv.y : qv.x) + kd[t * Nn + s];
            av = av > 0.f ? av : 0.2f * av;
            ex = __expf(av);
            off = ((unsigned)s << 8) | ((unsigned)t << 7);  // s*256 + t*128 bytes
        }
        shl[lane] = make_uint2(f2u(ex), off);
        exsum += ex;

        const int cnt = min(64, end - b);
        for (int j = 0; j < cnt; j += 32) {
            const uint2 p0 = shl[j + eighth];
            const uint2 p1 = shl[j + 8 + eighth];
            const uint2 p2 = shl[j + 16 + eighth];
            const uint2 p3 = shl[j + 24 + eighth];
            const uint4 v0 = *(const uint4*)(pb + (p0.y + lb));
            const uint4 v1 = *(const uint4*)(pb + (p1.y + lb));
            const uint4 v2 = *(const uint4*)(pb + (p2.y + lb));
            const uint4 v3 = *(const uint4*)(pb + (p3.y + lb));
            acc8(u2f(p0.x), v0, a);
            acc8(u2f(p1.x), v1, a);
            acc8(u2f(p2.x), v2, a);
            acc8(u2f(p3.x), v3, a);
        }
    }
#pragma unroll
    for (int o = 32; o; o >>= 1) exsum += __shfl_xor(exsum, o);
    const float inv = 1.f / (exsum + 1e-16f);
    if (lane == 0) inv_out[d] = inv;
#pragma unroll
    for (int q = 0; q < 8; ++q) {
        a[q] += __shfl_xor(a[q], 32);
        a[q] += __shfl_xor(a[q], 16);
        a[q] += __shfl_xor(a[q], 8);
    }
    if (eighth == 0) {
        float vv[8];
#pragma unroll
        for (int q = 0; q < 8; ++q) {
            const float e = a[q] * inv;
            vv[q] = e > 0.f ? e : expm1f(e);
        }
        float4 f0; f0.x = vv[0]; f0.y = vv[1]; f0.z = vv[2]; f0.w = vv[3];
        float4 f1; f1.x = vv[4]; f1.y = vv[5]; f1.z = vv[6]; f1.w = vv[7];
        *(float4*)&out[(long)d * 64 + (l7 << 3)] = f0;
        *(float4*)&out[(long)d * 64 + (l7 << 3) + 4] = f1;
        ushort8 hh, hl;
#pragma unroll
        for (int q = 0; q < 8; ++q) {
            const unsigned short hi = f2bf(vv[q]);
            hh[q] = hi; hl[q] = f2bf(vv[q] - bf2f(hi));
        }
        *(ushort8*)&h2h[(long)d * 64 + (l7 << 3)] = hh;
        *(ushort8*)&h2l[(long)d * 64 + (l7 << 3)] = hl;
    }
}

// -------- attention outputs: recompute alpha for both layers, one edge pass ----
// Identical FP expressions/inputs as the aggr kernels -> consistent softmax.
__global__ __launch_bounds__(256) void att_k(
    const int* __restrict__ srcv, const int* __restrict__ dstv,
    const int* __restrict__ et,
    const float* __restrict__ qd1, const float* __restrict__ kd1,
    const float* __restrict__ inv1,
    const float* __restrict__ qd2, const float* __restrict__ kd2,
    const float* __restrict__ inv2,
    float* __restrict__ att1, float* __restrict__ att2, int E, int Nn)
{
    const int e = blockIdx.x * 256 + threadIdx.x;
    if (e >= E) return;
    const int s = srcv[e], d = dstv[e], t = et[e];
    float x1 = qd1[2 * d + t] + kd1[t * Nn + s];
    x1 = x1 > 0.f ? x1 : 0.2f * x1;
    att1[e] = __expf(x1) * inv1[d];
    float x2 = qd2[2 * d + t] + kd2[t * Nn + s];
    x2 = x2 > 0.f ? x2 : 0.2f * x2;
    att2[e] = __expf(x2) * inv2[d];
}

extern "C" void kernel_launch(void* const* d_in, const int* in_sizes, int n_in,
                              void* d_out, int out_size, void* d_ws, size_t ws_size,
                              hipStream_t stream)
{
    const float* features = (const float*)d_in[0];
    const int*   eidx     = (const int*)d_in[1];
    const int*   etype    = (const int*)d_in[2];
    const float* W1       = (const float*)d_in[3];
    const float* q1       = (const float*)d_in[4];
    const float* k1       = (const float*)d_in[5];
    const float* W2       = (const float*)d_in[6];
    const float* q2       = (const float*)d_in[7];
    const float* k2       = (const float*)d_in[8];
    const float* dw1      = (const float*)d_in[9];
    const float* db1      = (const float*)d_in[10];
    const float* dw2      = (const float*)d_in[11];
    const float* db2      = (const float*)d_in[12];

    const int* srcv = eidx;
    const int* dstv = eidx + N_EDGE;

    float* out_h2 = (float*)d_out;                  // N x 64
    float* out_h3 = out_h2 + (long)N_NODES * OUT_D; // N x 256
    float* att1   = out_h3 + (long)N_NODES * IN_D;  // E
    float* att2   = att1 + N_EDGE;                  // E

    // ---- workspace carve-up ----
    // Liveness: rank aliases projb1's first 4 MB — rank dies at place_k, and
    // projb1 is first written by gemm_bf16_k which launches AFTER place_k.
    // inv1/inv2 live from aggr1/aggr2 until att_k; they sit in the dead
    // scan-scratch gap [53.5M, 57.3M).
    char* W = (char*)d_ws;
    int* rank = (int*)W;                                       // [0, 4M)  (aliases projb1)
    unsigned short* projb1 = (unsigned short*)(W);             // [0, 25.6M)
    unsigned short* projb2 = (unsigned short*)(W);             // alias
    unsigned short* hidh   = (unsigned short*)(W);             // [0, 12.8M) after aggr2
    unsigned short* hidl   = (unsigned short*)(W + 12800000);
    unsigned short* h1b    = (unsigned short*)(W + 25600000);  // [25.6M, 38.4M)
    unsigned short* h2h    = (unsigned short*)(W + 25600000 + 12800000);
    unsigned short* h2l    = (unsigned short*)(W + 25600000 + 19200000);
    float* qd1 = (float*)(W + 51200000);            // interleaved [node][2]
    float* kd1 = qd1 + 2 * N_NODES;
    float* qd2 = kd1 + 2 * N_NODES;
    float* kd2 = qd2 + 2 * N_NODES;
    int* cnt    = (int*)(kd2 + 2 * N_NODES);        // ends 53.0M
    int* offs   = cnt + N_NODES;                    // ends 53.200M
    int* bsum   = offs + N_NODES + 1;
    int* bpre   = bsum + 256;
    int* excl   = bpre + 256;                       // ends 53.402M
    float* inv1 = (float*)(W + 53500000);           // [53.5M, 53.7M)
    float* inv2 = inv1 + N_NODES;                   // [53.7M, 53.9M)
    unsigned* recs = (unsigned*)(W + 57300000);     // [57.3M, 61.3M)
    unsigned short* Wc1t = (unsigned short*)(W + 65300000);    // 65536 us
    unsigned short* Wc2t = Wc1t + 65536;                       // 16384 us
    unsigned short* dw1h = Wc2t + 16384;                       // 8192
    unsigned short* dw1l = dw1h + 8192;
    unsigned short* dw2h = dw1l + 8192;                        // 32768
    unsigned short* dw2l = dw2h + 32768;

    const int NB = (N_NODES + 255) / 256;

    // ---- prep: weight conversions (one kernel) + CSR build ----
    prep_k<<<480, 256, 0, stream>>>(W1, W2, dw1, dw2,
                                    Wc1t, Wc2t, dw1h, dw1l, dw2h, dw2l);

    hipMemsetAsync(cnt, 0, sizeof(int) * N_NODES, stream);
    rank_k<<<(N_EDGE + 255) / 256, 256, 0, stream>>>(dstv, cnt, rank, N_EDGE);
    scan1_k<<<NB, 256, 0, stream>>>(cnt, excl, bsum, N_NODES);
    scan2_k<<<1, 256, 0, stream>>>(bsum, bpre, NB);
    scan3_k<<<NB, 256, 0, stream>>>(excl, bpre, offs, N_NODES, N_EDGE);
    place_k<<<(N_EDGE + 255) / 256, 256, 0, stream>>>(
        srcv, dstv, etype, rank, offs, recs, N_EDGE);

    // ---- layer 1 (features converted fp32->bf16 inside gemm staging) ----
    gemm_bf16_k<4, true><<<dim3(2, (N_NODES + 127) / 128), 256, 0, stream>>>(
        nullptr, features, Wc1t, projb1, N_NODES, IN_D, 2 * HID_D);
    dotsB_k<128><<<(int)(((long)N_NODES * 64 + 255) / 256), 256, 0, stream>>>(
        projb1, q1, k1, qd1, kd1, N_NODES);
    aggr1_k<<<(N_NODES + 3) / 4, 256, 0, stream>>>(
        offs, recs, qd1, kd1, projb1, inv1, h1b, N_NODES);

    // ---- layer 2 ----
    gemm_bf16_k<4, false><<<dim3(1, (N_NODES + 127) / 128), 256, 0, stream>>>(
        h1b, nullptr, Wc2t, projb2, N_NODES, HID_D, 2 * OUT_D);
    dotsB_k<64><<<(int)(((long)N_NODES * 64 + 255) / 256), 256, 0, stream>>>(
        projb2, q2, k2, qd2, kd2, N_NODES);
    aggr2_k<<<(N_NODES + 3) / 4, 256, 0, stream>>>(
        offs, recs, qd2, kd2, projb2, inv2, out_h2, h2h, h2l, N_NODES);

    // ---- attention outputs (both layers, one pass over E) ----
    att_k<<<(N_EDGE + 255) / 256, 256, 0, stream>>>(
        srcv, dstv, etype, qd1, kd1, inv1, qd2, kd2, inv2, att1, att2,
        N_EDGE, N_NODES);

    // ---- decoder (split-bf16 MFMA, fp32-accurate) ----
    dec_gemm_k<4, true><<<dim3(1, (N_NODES + 127) / 128), 256, 0, stream>>>(
        h2h, h2l, dw1h, dw1l, db1, nullptr, hidh, hidl, N_NODES, OUT_D, HID_D);
    dec_gemm_k<4, false><<<dim3(2, (N_NODES + 127) / 128), 256, 0, stream>>>(
        hidh, hidl, dw2h, dw2l, db2, out_h3, nullptr, nullptr, N_NODES, HID_D, IN_D);
}